// Round 1
// baseline (1955.237 us; speedup 1.0000x reference)
//
#include <hip/hip_runtime.h>
#include <hip/hip_bf16.h>
#include <math.h>

// Problem: S=512, B=128, V=50257, D=300, H=512
#define S_LEN 512
#define B_N   128
#define D_EMB 300
#define KP    320   // D padded to multiple of 32 (zero-filled)
#define H_N   512

typedef __attribute__((ext_vector_type(8)))  short short8;       // 8 bf16 (4 VGPRs)
typedef __attribute__((ext_vector_type(8)))  unsigned short ushort8;
typedef __attribute__((ext_vector_type(4)))  float float4v;
typedef __attribute__((ext_vector_type(16))) float float16v;

__device__ __forceinline__ unsigned short f32_to_bf16(float f) {
  unsigned u = __float_as_uint(f);
  u = (u + 0x7fffu + ((u >> 16) & 1u)) >> 16;   // RNE
  return (unsigned short)u;
}
__device__ __forceinline__ float bf16_to_f32(unsigned short h) {
  return __uint_as_float(((unsigned)h) << 16);
}

// ---------------------------------------------------------------------------
// K1: embeds = embed_mat[ends]; xn = embeds / max(||embeds||,eps)
// writes xn as split bf16 (hi+lo), layout [b][s][KP], k 300..319 zero.
// ---------------------------------------------------------------------------
__global__ __launch_bounds__(256) void k1_embed_norm(
    const int* __restrict__ ends, const float* __restrict__ emb,
    unsigned short* __restrict__ xh, unsigned short* __restrict__ xl) {
  int wave = threadIdx.x >> 6, lane = threadIdx.x & 63;
  int vec = blockIdx.x * 4 + wave;            // vec = s*B + b (ends is [S][B])
  int b = vec & (B_N - 1), s = vec >> 7;
  int v = ends[vec];
  const float* row = emb + (size_t)v * D_EMB;
  float e0 = row[lane], e1 = row[lane + 64], e2 = row[lane + 128], e3 = row[lane + 192];
  float e4 = (lane + 256 < D_EMB) ? row[lane + 256] : 0.f;
  float ss = e0*e0 + e1*e1 + e2*e2 + e3*e3 + e4*e4;
  #pragma unroll
  for (int m = 1; m < 64; m <<= 1) ss += __shfl_xor(ss, m);
  float sc = 1.0f / fmaxf(sqrtf(ss), 1e-8f);
  size_t base = ((size_t)b * S_LEN + s) * KP;
  float xs[5] = { e0*sc, e1*sc, e2*sc, e3*sc, (lane + 256 < D_EMB) ? e4*sc : 0.f };
  #pragma unroll
  for (int i = 0; i < 5; ++i) {
    unsigned short hi = f32_to_bf16(xs[i]);
    unsigned short lo = f32_to_bf16(xs[i] - bf16_to_f32(hi));
    xh[base + lane + 64*i] = hi;
    xl[base + lane + 64*i] = lo;
  }
}

// ---------------------------------------------------------------------------
// K2: feats[i][b] = max_{j<i} dot(xn[i,b], xn[j,b]); feats[0]=0
// Split-bf16 MFMA 32x32x16 (hi*hi + hi*lo + lo*hi).
// R11: A-operand fragments loaded straight from global into registers
// (identical element mapping as the old LDS path; L2-hot after jc=0),
// LDS stages only B (22.5KB -> ~2x co-residency), grid is (b, ic) so all
// ic-chunks of a batch share one XCD L2 (same %8 mapping k3 relies on).
// ---------------------------------------------------------------------------
#define KC  80
#define LDP 88      // LDS row stride in ushorts (conflict-friendly, 16B aligned)

__global__ __launch_bounds__(256) void k2_feats(
    const unsigned short* __restrict__ xh, const unsigned short* __restrict__ xl,
    float* __restrict__ feats) {
  __shared__ __align__(16) unsigned short sBh[64*LDP], sBl[64*LDP];
  __shared__ float rbuf[4][32];
  int b   = blockIdx.x;          // 0..127 (b&7 selects XCD)
  int ic  = blockIdx.y;          // 0..7
  int tid = threadIdx.x;
  int wave = tid >> 6, lane = tid & 63;
  int itl = wave & 1, jtl = wave >> 1;
  int itg = ic * 2 + itl;        // global 32-row i-tile index
  size_t xbase = (size_t)b * S_LEN * KP;
  int arow0 = ic * 64;
  // my A row (m = lane&31) and k-quad offset
  const size_t arowoff = xbase + (size_t)(arow0 + itl * 32 + (lane & 31)) * KP
                       + (size_t)((lane >> 5) * 8);

  float rm[16];
  #pragma unroll
  for (int r = 0; r < 16; ++r) rm[r] = -INFINITY;

  for (int jc = 0; jc <= ic; ++jc) {
    int jt = jc * 2 + jtl;
    bool active = (jt <= itg);
    float16v acc;
    #pragma unroll
    for (int r = 0; r < 16; ++r) acc[r] = 0.f;

    for (int kc = 0; kc < 4; ++kc) {
      // A fragments: direct global->register (10 x 16B per lane)
      short8 a_h[5], a_l[5];
      #pragma unroll
      for (int ks = 0; ks < 5; ++ks) {
        size_t ga = arowoff + kc * KC + ks * 16;
        a_h[ks] = *(const short8*)&xh[ga];
        a_l[ks] = *(const short8*)&xl[ga];
      }
      __syncthreads();
      for (int u = tid; u < 640; u += 256) {     // 64 rows x 10 16B-segs (B only)
        int r = u / 10, sg = u % 10;
        size_t gb = xbase + (size_t)(jc*64 + r) * KP + kc*KC + sg*8;
        int la = r * LDP + sg * 8;
        *(ushort8*)&sBh[la] = *(const ushort8*)&xh[gb];
        *(ushort8*)&sBl[la] = *(const ushort8*)&xl[gb];
      }
      __syncthreads();
      if (active) {
        int br = (jtl*32 + (lane & 31)) * LDP;
        int kq = (lane >> 5) * 8;
        #pragma unroll
        for (int ks = 0; ks < 5; ++ks) {
          short8 b_h = *(const short8*)&sBh[br + ks*16 + kq];
          short8 b_l = *(const short8*)&sBl[br + ks*16 + kq];
          acc = __builtin_amdgcn_mfma_f32_32x32x16_bf16(a_h[ks], b_h, acc, 0, 0, 0);
          acc = __builtin_amdgcn_mfma_f32_32x32x16_bf16(a_h[ks], b_l, acc, 0, 0, 0);
          acc = __builtin_amdgcn_mfma_f32_32x32x16_bf16(a_l[ks], b_h, acc, 0, 0, 0);
        }
      }
    }
    if (active) {
      int colg = jt * 32 + (lane & 31);
      #pragma unroll
      for (int r = 0; r < 16; ++r) {
        int rowg = itg * 32 + (r & 3) + 8*(r >> 2) + 4*(lane >> 5);
        float v = acc[r];
        if (jt == itg && colg >= rowg) v = -INFINITY;  // causal: j<i
        rm[r] = fmaxf(rm[r], v);
      }
    }
  }
  #pragma unroll
  for (int r = 0; r < 16; ++r) {
    float v = rm[r];
    v = fmaxf(v, __shfl_xor(v, 1));
    v = fmaxf(v, __shfl_xor(v, 2));
    v = fmaxf(v, __shfl_xor(v, 4));
    v = fmaxf(v, __shfl_xor(v, 8));
    v = fmaxf(v, __shfl_xor(v, 16));
    rm[r] = v;
  }
  if ((lane & 31) == 0) {
    int half = lane >> 5;
    #pragma unroll
    for (int r = 0; r < 16; ++r)
      rbuf[wave][(r & 3) + 8*(r >> 2) + 4*half] = rm[r];
  }
  __syncthreads();
  if (tid < 64) {   // merge jt-parities, write feats
    int it2 = tid >> 5, rl = tid & 31;
    float v = fmaxf(rbuf[it2][rl], rbuf[it2 + 2][rl]);
    int i = ic * 64 + it2 * 32 + rl;
    feats[i * B_N + b] = (i == 0) ? 0.0f : v;
  }
}

// ---------------------------------------------------------------------------
// K3: GRU, persistent cooperative kernel. 256 WGs x 256 thr.
// R12: POISON-SPIN handoff replaces the flag protocol. The h words themselves
// are the synchronization variable: consumers spin per-8B-word until the word
// != POISON (0xFFFF bf16-hi is NaN, unreachable since |h|<=1; aligned 8B
// atomic stores/loads are untearable — same primitives R8 proved).
// Removes from the critical path: producer vmcnt(0) drain (deferred to just
// before NEXT step's stores, where it is free), flag store, flag-poll L2 hop,
// and the post-flag bulk h-load (the spin loads ARE the h-load).
// 4-buffer rotation (t&3): owner poisons buf[(t+2)&3] with its value stores;
// deadlock-free (all reads of that buffer's old values completed one step
// earlier by all-to-all data dependence); stale-read-free (poison@t drained
// before values@t+1 are issued; consumers spin on the buffer only at t+3).
// Buffers memset to poison every launch (graph-replay safe).
// LEDGER: per-wave flag fanouts fast-fail 3/3 (R5/R6/R9); counter-RMW flags
// regress (R10). This scheme is per-word SELF-signaling — no word's
// readiness is inferred from another location.
// ---------------------------------------------------------------------------
#define HW64 (B_N * H_N / 2)   // 8B words per buffer
#define NBUF 4
#define POISON64 0xFFFFFFFFFFFFFFFFull

__global__ __launch_bounds__(256, 1) void k3_gru(
    const float* __restrict__ feats,
    const float* __restrict__ w_ih, const float* __restrict__ w_hh,
    const float* __restrict__ b_ih, const float* __restrict__ b_hh,
    const float* __restrict__ fc_w, const float* __restrict__ fc_b,
    unsigned long long* __restrict__ hq, float* __restrict__ out) {
  __shared__ float red[4][3][16][17];
  __shared__ float osum[256];
  int tid = threadIdx.x;
  int wave = tid >> 6, lane = tid & 63;
  int g = blockIdx.x & 7, s = blockIdx.x >> 3;

  // --- stationary W_hh fragments in registers (B-operand: n=lane&15, k=quad*8+j)
  short8 wfh[3][4], wfl[3][4];
  {
    int nloc = lane & 15;
    int kq = (lane >> 4) * 8;
    #pragma unroll
    for (int gt = 0; gt < 3; ++gt) {
      const float* wr = w_hh + (size_t)(gt * H_N + s * 16 + nloc) * H_N;
      #pragma unroll
      for (int ks = 0; ks < 4; ++ks) {
        int k0 = wave * 128 + ks * 32 + kq;
        short8 h8, l8;
        #pragma unroll
        for (int j = 0; j < 8; ++j) {
          float wv = wr[k0 + j];
          unsigned short hi = f32_to_bf16(wv);
          unsigned short lo = f32_to_bf16(wv - bf16_to_f32(hi));
          h8[j] = (short)hi; l8[j] = (short)lo;
        }
        wfh[gt][ks] = h8; wfl[gt][ks] = l8;
      }
    }
  }
  // --- per-thread gate constants: thread = (bb, jj)
  int bb = tid >> 4, jj = tid & 15;
  int jr = s * 16 + jj;
  float wihr = w_ih[jr], wihz = w_ih[H_N + jr], wihn = w_ih[2*H_N + jr];
  float bir = b_ih[jr],  biz = b_ih[H_N + jr],  bin_ = b_ih[2*H_N + jr];
  float bhr = b_hh[jr],  bhz = b_hh[H_N + jr],  bhn = b_hh[2*H_N + jr];
  float fcw = fc_w[jr];
  int gb = g * 16 + bb;
  float h_old = 0.f;
  int arow = g * 16 + (lane & 15);              // A-operand m = batch
  int kqa = (lane >> 4) * 8;
  size_t widx = ((size_t)gb * H_N + jr) >> 1;   // 8B word index (jj even only)

  for (int t = 0; t < S_LEN; ++t) {
    // feats load hoisted above the spin — independent, overlaps it
    float x = feats[t * B_N + gb];
    float sr = 0.f, sz = 0.f, sn = 0.f;
    if (t > 0) {
      const unsigned long long* hb =
          hq + (size_t)((t - 1) & 3) * HW64 + (size_t)arow * (H_N / 2);
      // ---- per-word poison spin: word != POISON  <=>  h_{t-1} word landed
      unsigned long long w64[4][4];
      unsigned pend = 0xFFFFu;
      while (pend) {
        #pragma unroll
        for (int ks = 0; ks < 4; ++ks) {
          int kw = (wave * 128 + ks * 32 + kqa) >> 1;
          #pragma unroll
          for (int q = 0; q < 4; ++q)
            if (pend & (1u << (ks * 4 + q)))
              w64[ks][q] = __hip_atomic_load(hb + kw + q,
                  __ATOMIC_RELAXED, __HIP_MEMORY_SCOPE_AGENT);
        }
        unsigned np = 0;
        #pragma unroll
        for (int ks = 0; ks < 4; ++ks) {
          #pragma unroll
          for (int q = 0; q < 4; ++q)
            if (w64[ks][q] == POISON64) np |= 1u << (ks * 4 + q);
        }
        pend = np;
        if (pend) __builtin_amdgcn_s_sleep(1);
      }
      asm volatile("" ::: "memory");
      // ---- unpack [hi pair | lo pair]
      short8 ah[4], al[4];
      #pragma unroll
      for (int ks = 0; ks < 4; ++ks) {
        union { unsigned u[4]; short8 v; } uh, ul;
        #pragma unroll
        for (int q = 0; q < 4; ++q) {
          unsigned long long w = w64[ks][q];
          uh.u[q] = (unsigned)w;
          ul.u[q] = (unsigned)(w >> 32);
        }
        ah[ks] = uh.v; al[ks] = ul.v;
      }
      float4v a0, a1, a2;
      #pragma unroll
      for (int r = 0; r < 4; ++r) { a0[r] = 0.f; a1[r] = 0.f; a2[r] = 0.f; }
      #pragma unroll
      for (int ks = 0; ks < 4; ++ks) {
        a0 = __builtin_amdgcn_mfma_f32_16x16x32_bf16(ah[ks], wfh[0][ks], a0, 0,0,0);
        a1 = __builtin_amdgcn_mfma_f32_16x16x32_bf16(ah[ks], wfh[1][ks], a1, 0,0,0);
        a2 = __builtin_amdgcn_mfma_f32_16x16x32_bf16(ah[ks], wfh[2][ks], a2, 0,0,0);
        a0 = __builtin_amdgcn_mfma_f32_16x16x32_bf16(ah[ks], wfl[0][ks], a0, 0,0,0);
        a1 = __builtin_amdgcn_mfma_f32_16x16x32_bf16(ah[ks], wfl[1][ks], a1, 0,0,0);
        a2 = __builtin_amdgcn_mfma_f32_16x16x32_bf16(ah[ks], wfl[2][ks], a2, 0,0,0);
        a0 = __builtin_amdgcn_mfma_f32_16x16x32_bf16(al[ks], wfh[0][ks], a0, 0,0,0);
        a1 = __builtin_amdgcn_mfma_f32_16x16x32_bf16(al[ks], wfh[1][ks], a1, 0,0,0);
        a2 = __builtin_amdgcn_mfma_f32_16x16x32_bf16(al[ks], wfh[2][ks], a2, 0,0,0);
      }
      // barrier #A: protect red[] from previous step's readers (the flag
      // lockstep used to provide this ordering implicitly)
      __syncthreads();
      // C/D: row(batch)=(lane>>4)*4+reg, col(j)=lane&15. Scalar writes, padded.
      int colw = lane & 15, roww = (lane >> 4) * 4;
      #pragma unroll
      for (int r = 0; r < 4; ++r) {
        red[wave][0][roww + r][colw] = a0[r];
        red[wave][1][roww + r][colw] = a1[r];
        red[wave][2][roww + r][colw] = a2[r];
      }
      __syncthreads();
      sr = red[0][0][bb][jj] + red[1][0][bb][jj] + red[2][0][bb][jj] + red[3][0][bb][jj];
      sz = red[0][1][bb][jj] + red[1][1][bb][jj] + red[2][1][bb][jj] + red[3][1][bb][jj];
      sn = red[0][2][bb][jj] + red[1][2][bb][jj] + red[2][2][bb][jj] + red[3][2][bb][jj];
    }
    // gates: exact identities on fast exp; clamp to dodge inf/inf
    float ar_ = fminf(fmaxf(x * wihr + bir + sr + bhr, -30.f), 30.f);
    float az_ = fminf(fmaxf(x * wihz + biz + sz + bhz, -30.f), 30.f);
    float r_ = __builtin_amdgcn_rcpf(1.f + __expf(-ar_));
    float z_ = __builtin_amdgcn_rcpf(1.f + __expf(-az_));
    float an_ = fminf(fmaxf(x * wihn + bin_ + r_ * (sn + bhn), -30.f), 30.f);
    float en = __expf(-2.f * an_);
    float n_ = (1.f - en) * __builtin_amdgcn_rcpf(1.f + en);
    float h_new = (1.f - z_) * n_ + z_ * h_old;
    h_old = h_new;
    if (t < S_LEN - 1) {
      // deferred drain: completes stores@t-1 (values + poison) BEFORE any
      // store@t is issued -> poison@t-1 globally visible before values@t.
      // Off the signal path: those stores are ~a full step old by now.
      asm volatile("s_waitcnt vmcnt(0)" ::: "memory");
      // WORKGROUP-scope packed 8B store: [hi(j0)|hi(j1) | lo(j0)|lo(j1)]
      unsigned short hi16 = f32_to_bf16(h_new);
      unsigned short lo16 = f32_to_bf16(h_new - bf16_to_f32(hi16));
      unsigned packed = (unsigned)hi16 | ((unsigned)lo16 << 16);
      unsigned other = (unsigned)__shfl_xor((int)packed, 1);
      if ((jj & 1) == 0) {
        unsigned u0 = (packed & 0xffffu) | (other << 16);        // hi pair
        unsigned u1 = (packed >> 16) | (other & 0xffff0000u);    // lo pair
        unsigned long long wv = (unsigned long long)u0 | ((unsigned long long)u1 << 32);
        __hip_atomic_store(hq + (size_t)(t & 3) * HW64 + widx, wv,
                           __ATOMIC_RELAXED, __HIP_MEMORY_SCOPE_WORKGROUP);
        // re-arm the buffer that will carry h_{t+2}
        __hip_atomic_store(hq + (size_t)((t + 2) & 3) * HW64 + widx, POISON64,
                           __ATOMIC_RELAXED, __HIP_MEMORY_SCOPE_WORKGROUP);
      }
    }
  }
  // --- epilogue: out[b] = h_last . fc_w + fc_b
  osum[tid] = h_old * fcw;
  __syncthreads();
  if (jj == 0) {
    float acc = 0.f;
    #pragma unroll
    for (int q = 0; q < 16; ++q) acc += osum[bb * 16 + q];
    if (s == 0) acc += fc_b[0];
    atomicAdd(&out[gb], acc);
  }
}

// ---------------------------------------------------------------------------
extern "C" void kernel_launch(void* const* d_in, const int* in_sizes, int n_in,
                              void* d_out, int out_size, void* d_ws, size_t ws_size,
                              hipStream_t stream) {
  (void)in_sizes; (void)n_in; (void)out_size; (void)ws_size;
  const int*   ends = (const int*)d_in[1];
  const float* emb  = (const float*)d_in[3];
  const float* w_ih = (const float*)d_in[4];
  const float* w_hh = (const float*)d_in[5];
  const float* b_ih = (const float*)d_in[6];
  const float* b_hh = (const float*)d_in[7];
  const float* fc_w = (const float*)d_in[8];
  const float* fc_b = (const float*)d_in[9];
  float* out = (float*)d_out;

  size_t xn_elems = (size_t)B_N * S_LEN * KP;
  unsigned short* xh = (unsigned short*)d_ws;
  unsigned short* xl = xh + xn_elems;
  float* feats = (float*)(xl + xn_elems);
  unsigned long long* hq = (unsigned long long*)(feats + S_LEN * B_N);

  hipMemsetAsync(out, 0, sizeof(float) * B_N, stream);
  // arm ALL buffers with poison every launch (graph-replay safe)
  hipMemsetAsync(hq, 0xFF, (size_t)NBUF * HW64 * 8, stream);

  k1_embed_norm<<<dim3(S_LEN * B_N / 4), dim3(256), 0, stream>>>(ends, emb, xh, xl);
  k2_feats<<<dim3(B_N, 8), dim3(256), 0, stream>>>(xh, xl, feats);

  void* args[] = { (void*)&feats, (void*)&w_ih, (void*)&w_hh, (void*)&b_ih,
                   (void*)&b_hh, (void*)&fc_w, (void*)&fc_b,
                   (void*)&hq, (void*)&out };
  hipLaunchCooperativeKernel((void*)k3_gru, dim3(256), dim3(256), args, 0, stream);
}

// Round 2
// 1368.225 us; speedup vs baseline: 1.4290x; 1.4290x over previous
//
#include <hip/hip_runtime.h>
#include <hip/hip_bf16.h>
#include <math.h>

// Problem: S=512, B=128, V=50257, D=300, H=512
#define S_LEN 512
#define B_N   128
#define D_EMB 300
#define KP    320   // D padded to multiple of 32 (zero-filled)
#define H_N   512

typedef __attribute__((ext_vector_type(8)))  short short8;       // 8 bf16 (4 VGPRs)
typedef __attribute__((ext_vector_type(8)))  unsigned short ushort8;
typedef __attribute__((ext_vector_type(4)))  unsigned int uint4v;
typedef __attribute__((ext_vector_type(4)))  float float4v;
typedef __attribute__((ext_vector_type(16))) float float16v;

__device__ __forceinline__ unsigned short f32_to_bf16(float f) {
  unsigned u = __float_as_uint(f);
  u = (u + 0x7fffu + ((u >> 16) & 1u)) >> 16;   // RNE
  return (unsigned short)u;
}
__device__ __forceinline__ float bf16_to_f32(unsigned short h) {
  return __uint_as_float(((unsigned)h) << 16);
}

// ---------------------------------------------------------------------------
// K1: embeds = embed_mat[ends]; xn = embeds / max(||embeds||,eps)
// writes xn as split bf16 (hi+lo), layout [b][s][KP], k 300..319 zero.
// ---------------------------------------------------------------------------
__global__ __launch_bounds__(256) void k1_embed_norm(
    const int* __restrict__ ends, const float* __restrict__ emb,
    unsigned short* __restrict__ xh, unsigned short* __restrict__ xl) {
  int wave = threadIdx.x >> 6, lane = threadIdx.x & 63;
  int vec = blockIdx.x * 4 + wave;            // vec = s*B + b (ends is [S][B])
  int b = vec & (B_N - 1), s = vec >> 7;
  int v = ends[vec];
  const float* row = emb + (size_t)v * D_EMB;
  float e0 = row[lane], e1 = row[lane + 64], e2 = row[lane + 128], e3 = row[lane + 192];
  float e4 = (lane + 256 < D_EMB) ? row[lane + 256] : 0.f;
  float ss = e0*e0 + e1*e1 + e2*e2 + e3*e3 + e4*e4;
  #pragma unroll
  for (int m = 1; m < 64; m <<= 1) ss += __shfl_xor(ss, m);
  float sc = 1.0f / fmaxf(sqrtf(ss), 1e-8f);
  size_t base = ((size_t)b * S_LEN + s) * KP;
  float xs[5] = { e0*sc, e1*sc, e2*sc, e3*sc, (lane + 256 < D_EMB) ? e4*sc : 0.f };
  #pragma unroll
  for (int i = 0; i < 5; ++i) {
    unsigned short hi = f32_to_bf16(xs[i]);
    unsigned short lo = f32_to_bf16(xs[i] - bf16_to_f32(hi));
    xh[base + lane + 64*i] = hi;
    xl[base + lane + 64*i] = lo;
  }
}

// ---------------------------------------------------------------------------
// K2: feats[i][b] = max_{j<i} dot(xn[i,b], xn[j,b]); feats[0]=0
// Split-bf16 MFMA 32x32x16 (hi*hi + hi*lo + lo*hi).
// R11: A-operand fragments loaded straight from global into registers
// (identical element mapping as the old LDS path; L2-hot after jc=0),
// LDS stages only B (22.5KB -> ~2x co-residency), grid is (b, ic) so all
// ic-chunks of a batch share one XCD L2 (same %8 mapping k3 relies on).
// ---------------------------------------------------------------------------
#define KC  80
#define LDP 88      // LDS row stride in ushorts (conflict-friendly, 16B aligned)

__global__ __launch_bounds__(256) void k2_feats(
    const unsigned short* __restrict__ xh, const unsigned short* __restrict__ xl,
    float* __restrict__ feats) {
  __shared__ __align__(16) unsigned short sBh[64*LDP], sBl[64*LDP];
  __shared__ float rbuf[4][32];
  int b   = blockIdx.x;          // 0..127 (b&7 selects XCD)
  int ic  = blockIdx.y;          // 0..7
  int tid = threadIdx.x;
  int wave = tid >> 6, lane = tid & 63;
  int itl = wave & 1, jtl = wave >> 1;
  int itg = ic * 2 + itl;        // global 32-row i-tile index
  size_t xbase = (size_t)b * S_LEN * KP;
  int arow0 = ic * 64;
  // my A row (m = lane&31) and k-quad offset
  const size_t arowoff = xbase + (size_t)(arow0 + itl * 32 + (lane & 31)) * KP
                       + (size_t)((lane >> 5) * 8);

  float rm[16];
  #pragma unroll
  for (int r = 0; r < 16; ++r) rm[r] = -INFINITY;

  for (int jc = 0; jc <= ic; ++jc) {
    int jt = jc * 2 + jtl;
    bool active = (jt <= itg);
    float16v acc;
    #pragma unroll
    for (int r = 0; r < 16; ++r) acc[r] = 0.f;

    for (int kc = 0; kc < 4; ++kc) {
      // A fragments: direct global->register (10 x 16B per lane)
      short8 a_h[5], a_l[5];
      #pragma unroll
      for (int ks = 0; ks < 5; ++ks) {
        size_t ga = arowoff + kc * KC + ks * 16;
        a_h[ks] = *(const short8*)&xh[ga];
        a_l[ks] = *(const short8*)&xl[ga];
      }
      __syncthreads();
      for (int u = tid; u < 640; u += 256) {     // 64 rows x 10 16B-segs (B only)
        int r = u / 10, sg = u % 10;
        size_t gb = xbase + (size_t)(jc*64 + r) * KP + kc*KC + sg*8;
        int la = r * LDP + sg * 8;
        *(ushort8*)&sBh[la] = *(const ushort8*)&xh[gb];
        *(ushort8*)&sBl[la] = *(const ushort8*)&xl[gb];
      }
      __syncthreads();
      if (active) {
        int br = (jtl*32 + (lane & 31)) * LDP;
        int kq = (lane >> 5) * 8;
        #pragma unroll
        for (int ks = 0; ks < 5; ++ks) {
          short8 b_h = *(const short8*)&sBh[br + ks*16 + kq];
          short8 b_l = *(const short8*)&sBl[br + ks*16 + kq];
          acc = __builtin_amdgcn_mfma_f32_32x32x16_bf16(a_h[ks], b_h, acc, 0, 0, 0);
          acc = __builtin_amdgcn_mfma_f32_32x32x16_bf16(a_h[ks], b_l, acc, 0, 0, 0);
          acc = __builtin_amdgcn_mfma_f32_32x32x16_bf16(a_l[ks], b_h, acc, 0, 0, 0);
        }
      }
    }
    if (active) {
      int colg = jt * 32 + (lane & 31);
      #pragma unroll
      for (int r = 0; r < 16; ++r) {
        int rowg = itg * 32 + (r & 3) + 8*(r >> 2) + 4*(lane >> 5);
        float v = acc[r];
        if (jt == itg && colg >= rowg) v = -INFINITY;  // causal: j<i
        rm[r] = fmaxf(rm[r], v);
      }
    }
  }
  #pragma unroll
  for (int r = 0; r < 16; ++r) {
    float v = rm[r];
    v = fmaxf(v, __shfl_xor(v, 1));
    v = fmaxf(v, __shfl_xor(v, 2));
    v = fmaxf(v, __shfl_xor(v, 4));
    v = fmaxf(v, __shfl_xor(v, 8));
    v = fmaxf(v, __shfl_xor(v, 16));
    rm[r] = v;
  }
  if ((lane & 31) == 0) {
    int half = lane >> 5;
    #pragma unroll
    for (int r = 0; r < 16; ++r)
      rbuf[wave][(r & 3) + 8*(r >> 2) + 4*half] = rm[r];
  }
  __syncthreads();
  if (tid < 64) {   // merge jt-parities, write feats
    int it2 = tid >> 5, rl = tid & 31;
    float v = fmaxf(rbuf[it2][rl], rbuf[it2 + 2][rl]);
    int i = ic * 64 + it2 * 32 + rl;
    feats[i * B_N + b] = (i == 0) ? 0.0f : v;
  }
}

// ---------------------------------------------------------------------------
// K3: GRU, persistent cooperative kernel. 256 WGs x 256 thr.
// FROZEN at the R8 skeleton (benched 1464us, absmax 0.0, 3/3 reliable):
//   wg-scope producer stores (h + flag) -> dirty in shared XCD L2
//   (WRITE_SIZE 135MB->0.5MB proven); agent-scope relaxed reads (L1-bypass,
//   L2-hit); per-WG flag bars[g*32+s]; all-wave 32-flag poll with s_sleep;
//   post-store vmcnt(0) + __syncthreads + tid0 flag store.
// LEDGER: per-wave flag fanouts fast-fail 3/3 (R5/R6/R9, mechanism unknown);
// counter-RMW flags regress (R10: atomics write through, serialize);
// poison-spin data-as-signal regresses +16% (R12: spin traffic hammers
// in-flux L2 lines, VALU-heavy retries, doubled writes) — signal via FEW
// words, keep spin traffic minimal.
// R13 (this round): consumer h-load rewritten as 8x global_load_dwordx4
// (sc1 = L1-bypass, values are flag-protected so atomicity not needed):
// the old 16x 8B loads had same-row lanes at 32B stride -> 25% of each 64B
// L2 segment used; dwordx4 pairs -> 50% + 2x fewer VMEM instrs + one vmcnt.
// Cuts the ~1MB/step/XCD h fan-out's segment traffic in half and relieves
// L2 queue pressure on the producer store-ack path.
// ---------------------------------------------------------------------------
#define HW64 (B_N * H_N / 2)   // 8B words per buffer

__global__ __launch_bounds__(256, 1) void k3_gru(
    const float* __restrict__ feats,
    const float* __restrict__ w_ih, const float* __restrict__ w_hh,
    const float* __restrict__ b_ih, const float* __restrict__ b_hh,
    const float* __restrict__ fc_w, const float* __restrict__ fc_b,
    unsigned long long* __restrict__ hq, unsigned int* __restrict__ bars,
    float* __restrict__ out) {
  __shared__ float red[4][3][16][17];
  __shared__ float osum[256];
  int tid = threadIdx.x;
  int wave = tid >> 6, lane = tid & 63;
  int g = blockIdx.x & 7, s = blockIdx.x >> 3;

  // --- stationary W_hh fragments in registers (B-operand: n=lane&15, k=quad*8+j)
  short8 wfh[3][4], wfl[3][4];
  {
    int nloc = lane & 15;
    int kq = (lane >> 4) * 8;
    #pragma unroll
    for (int gt = 0; gt < 3; ++gt) {
      const float* wr = w_hh + (size_t)(gt * H_N + s * 16 + nloc) * H_N;
      #pragma unroll
      for (int ks = 0; ks < 4; ++ks) {
        int k0 = wave * 128 + ks * 32 + kq;
        short8 h8, l8;
        #pragma unroll
        for (int j = 0; j < 8; ++j) {
          float wv = wr[k0 + j];
          unsigned short hi = f32_to_bf16(wv);
          unsigned short lo = f32_to_bf16(wv - bf16_to_f32(hi));
          h8[j] = (short)hi; l8[j] = (short)lo;
        }
        wfh[gt][ks] = h8; wfl[gt][ks] = l8;
      }
    }
  }
  // --- per-thread gate constants: thread = (bb, jj)
  int bb = tid >> 4, jj = tid & 15;
  int jr = s * 16 + jj;
  float wihr = w_ih[jr], wihz = w_ih[H_N + jr], wihn = w_ih[2*H_N + jr];
  float bir = b_ih[jr],  biz = b_ih[H_N + jr],  bin_ = b_ih[2*H_N + jr];
  float bhr = b_hh[jr],  bhz = b_hh[H_N + jr],  bhn = b_hh[2*H_N + jr];
  float fcw = fc_w[jr];
  int gb = g * 16 + bb;
  float h_old = 0.f;
  const unsigned int* fp = bars + g * 32 + (lane & 31);  // this group's 32 flags
  unsigned int* myflag = bars + g * 32 + s;
  int arow = g * 16 + (lane & 15);              // A-operand m = batch
  size_t widx = ((size_t)gb * H_N + jr) >> 1;   // 8B word index (jj even only)
  // R13: per-lane fragment base = hb + wave*64 + quad*4 (words); the 16
  // needed words per lane are 4 contiguous per ks at word offsets ks*16.
  const int lanewoff = wave * 64 + (lane >> 4) * 4;

  for (int t = 0; t < S_LEN; ++t) {
    // feats load hoisted above the poll — independent, overlaps the spin
    float x = feats[t * B_N + gb];
    float sr = 0.f, sz = 0.f, sn = 0.f;
    if (t > 0) {
      // ---- wait: all 32 WGs stored h_{t-1} (flag >= t). every wave polls.
      {
        const unsigned tgt = (unsigned)t;
        for (;;) {
          unsigned f = __hip_atomic_load(fp, __ATOMIC_RELAXED, __HIP_MEMORY_SCOPE_AGENT);
          if (__ballot(f < tgt) == 0ull) break;
          __builtin_amdgcn_s_sleep(1);
        }
        asm volatile("" ::: "memory");
      }
      const unsigned long long* hb =
          hq + (size_t)((t - 1) & 1) * HW64 + (size_t)arow * (H_N / 2);
      const unsigned long long* p0 = hb + lanewoff;
      // R13: 8x dwordx4 sc1 (L1-bypass) + single vmcnt. Word layout per ks:
      // words ks*16 + quad*4 + {0..3}  ->  byte offsets ks*128 + {0,16}.
      uint4v rA0, rB0, rA1, rB1, rA2, rB2, rA3, rB3;
      asm volatile(
        "global_load_dwordx4 %0, %8, off sc1\n\t"
        "global_load_dwordx4 %1, %8, off offset:16 sc1\n\t"
        "global_load_dwordx4 %2, %8, off offset:128 sc1\n\t"
        "global_load_dwordx4 %3, %8, off offset:144 sc1\n\t"
        "global_load_dwordx4 %4, %8, off offset:256 sc1\n\t"
        "global_load_dwordx4 %5, %8, off offset:272 sc1\n\t"
        "global_load_dwordx4 %6, %8, off offset:384 sc1\n\t"
        "global_load_dwordx4 %7, %8, off offset:400 sc1\n\t"
        "s_waitcnt vmcnt(0)"
        : "=&v"(rA0), "=&v"(rB0), "=&v"(rA1), "=&v"(rB1),
          "=&v"(rA2), "=&v"(rB2), "=&v"(rA3), "=&v"(rB3)
        : "v"(p0)
        : "memory");
      // ---- unpack: word = [hi pair | lo pair]; uh = low dwords, ul = high
      short8 ah[4], al[4];
      {
        union U { unsigned u[4]; short8 v; } uh, ul;
        uh.u[0] = rA0.x; uh.u[1] = rA0.z; uh.u[2] = rB0.x; uh.u[3] = rB0.z;
        ul.u[0] = rA0.y; ul.u[1] = rA0.w; ul.u[2] = rB0.y; ul.u[3] = rB0.w;
        ah[0] = uh.v; al[0] = ul.v;
        uh.u[0] = rA1.x; uh.u[1] = rA1.z; uh.u[2] = rB1.x; uh.u[3] = rB1.z;
        ul.u[0] = rA1.y; ul.u[1] = rA1.w; ul.u[2] = rB1.y; ul.u[3] = rB1.w;
        ah[1] = uh.v; al[1] = ul.v;
        uh.u[0] = rA2.x; uh.u[1] = rA2.z; uh.u[2] = rB2.x; uh.u[3] = rB2.z;
        ul.u[0] = rA2.y; ul.u[1] = rA2.w; ul.u[2] = rB2.y; ul.u[3] = rB2.w;
        ah[2] = uh.v; al[2] = ul.v;
        uh.u[0] = rA3.x; uh.u[1] = rA3.z; uh.u[2] = rB3.x; uh.u[3] = rB3.z;
        ul.u[0] = rA3.y; ul.u[1] = rA3.w; ul.u[2] = rB3.y; ul.u[3] = rB3.w;
        ah[3] = uh.v; al[3] = ul.v;
      }
      float4v a0, a1, a2;
      #pragma unroll
      for (int r = 0; r < 4; ++r) { a0[r] = 0.f; a1[r] = 0.f; a2[r] = 0.f; }
      #pragma unroll
      for (int ks = 0; ks < 4; ++ks) {
        a0 = __builtin_amdgcn_mfma_f32_16x16x32_bf16(ah[ks], wfh[0][ks], a0, 0,0,0);
        a1 = __builtin_amdgcn_mfma_f32_16x16x32_bf16(ah[ks], wfh[1][ks], a1, 0,0,0);
        a2 = __builtin_amdgcn_mfma_f32_16x16x32_bf16(ah[ks], wfh[2][ks], a2, 0,0,0);
        a0 = __builtin_amdgcn_mfma_f32_16x16x32_bf16(ah[ks], wfl[0][ks], a0, 0,0,0);
        a1 = __builtin_amdgcn_mfma_f32_16x16x32_bf16(ah[ks], wfl[1][ks], a1, 0,0,0);
        a2 = __builtin_amdgcn_mfma_f32_16x16x32_bf16(ah[ks], wfl[2][ks], a2, 0,0,0);
        a0 = __builtin_amdgcn_mfma_f32_16x16x32_bf16(al[ks], wfh[0][ks], a0, 0,0,0);
        a1 = __builtin_amdgcn_mfma_f32_16x16x32_bf16(al[ks], wfh[1][ks], a1, 0,0,0);
        a2 = __builtin_amdgcn_mfma_f32_16x16x32_bf16(al[ks], wfh[2][ks], a2, 0,0,0);
      }
      // C/D: row(batch)=(lane>>4)*4+reg, col(j)=lane&15. Scalar writes, padded.
      int colw = lane & 15, roww = (lane >> 4) * 4;
      #pragma unroll
      for (int r = 0; r < 4; ++r) {
        red[wave][0][roww + r][colw] = a0[r];
        red[wave][1][roww + r][colw] = a1[r];
        red[wave][2][roww + r][colw] = a2[r];
      }
      __syncthreads();
      sr = red[0][0][bb][jj] + red[1][0][bb][jj] + red[2][0][bb][jj] + red[3][0][bb][jj];
      sz = red[0][1][bb][jj] + red[1][1][bb][jj] + red[2][1][bb][jj] + red[3][1][bb][jj];
      sn = red[0][2][bb][jj] + red[1][2][bb][jj] + red[2][2][bb][jj] + red[3][2][bb][jj];
    }
    // gates: exact identities on fast exp; clamp to dodge inf/inf
    float ar_ = fminf(fmaxf(x * wihr + bir + sr + bhr, -30.f), 30.f);
    float az_ = fminf(fmaxf(x * wihz + biz + sz + bhz, -30.f), 30.f);
    float r_ = __builtin_amdgcn_rcpf(1.f + __expf(-ar_));
    float z_ = __builtin_amdgcn_rcpf(1.f + __expf(-az_));
    float an_ = fminf(fmaxf(x * wihn + bin_ + r_ * (sn + bhn), -30.f), 30.f);
    float en = __expf(-2.f * an_);
    float n_ = (1.f - en) * __builtin_amdgcn_rcpf(1.f + en);
    float h_new = (1.f - z_) * n_ + z_ * h_old;
    h_old = h_new;
    if (t < S_LEN - 1) {
      // WORKGROUP-scope packed 8B store: [hi(j0)|hi(j1) | lo(j0)|lo(j1)]
      unsigned short hi16 = f32_to_bf16(h_new);
      unsigned short lo16 = f32_to_bf16(h_new - bf16_to_f32(hi16));
      unsigned packed = (unsigned)hi16 | ((unsigned)lo16 << 16);
      unsigned other = (unsigned)__shfl_xor((int)packed, 1);
      if ((jj & 1) == 0) {
        unsigned u0 = (packed & 0xffffu) | (other << 16);        // hi pair
        unsigned u1 = (packed >> 16) | (other & 0xffff0000u);    // lo pair
        unsigned long long wv = (unsigned long long)u0 | ((unsigned long long)u1 << 32);
        __hip_atomic_store(hq + (size_t)(t & 1) * HW64 + widx, wv,
                           __ATOMIC_RELAXED, __HIP_MEMORY_SCOPE_WORKGROUP);
      }
      // drain own stores (ack at L2), WG barrier, then flag (wg-scope)
      asm volatile("s_waitcnt vmcnt(0)" ::: "memory");
      __syncthreads();
      if (tid == 0)
        __hip_atomic_store(myflag, (unsigned)(t + 1),
                           __ATOMIC_RELAXED, __HIP_MEMORY_SCOPE_WORKGROUP);
    }
  }
  // --- epilogue: out[b] = h_last . fc_w + fc_b
  osum[tid] = h_old * fcw;
  __syncthreads();
  if (jj == 0) {
    float acc = 0.f;
    #pragma unroll
    for (int q = 0; q < 16; ++q) acc += osum[bb * 16 + q];
    if (s == 0) acc += fc_b[0];
    atomicAdd(&out[gb], acc);
  }
}

// ---------------------------------------------------------------------------
extern "C" void kernel_launch(void* const* d_in, const int* in_sizes, int n_in,
                              void* d_out, int out_size, void* d_ws, size_t ws_size,
                              hipStream_t stream) {
  (void)in_sizes; (void)n_in; (void)out_size; (void)ws_size;
  const int*   ends = (const int*)d_in[1];
  const float* emb  = (const float*)d_in[3];
  const float* w_ih = (const float*)d_in[4];
  const float* w_hh = (const float*)d_in[5];
  const float* b_ih = (const float*)d_in[6];
  const float* b_hh = (const float*)d_in[7];
  const float* fc_w = (const float*)d_in[8];
  const float* fc_b = (const float*)d_in[9];
  float* out = (float*)d_out;

  size_t xn_elems = (size_t)B_N * S_LEN * KP;
  unsigned short* xh = (unsigned short*)d_ws;
  unsigned short* xl = xh + xn_elems;
  float* feats = (float*)(xl + xn_elems);
  unsigned long long* hq = (unsigned long long*)(feats + S_LEN * B_N);
  unsigned int* bars = (unsigned int*)(hq + 2 * (size_t)HW64);

  hipMemsetAsync(out, 0, sizeof(float) * B_N, stream);
  hipMemsetAsync(bars, 0, 4096, stream);   // 8 groups x 32 WG flags

  k1_embed_norm<<<dim3(S_LEN * B_N / 4), dim3(256), 0, stream>>>(ends, emb, xh, xl);
  k2_feats<<<dim3(B_N, 8), dim3(256), 0, stream>>>(xh, xl, feats);

  void* args[] = { (void*)&feats, (void*)&w_ih, (void*)&w_hh, (void*)&b_ih,
                   (void*)&b_hh, (void*)&fc_w, (void*)&fc_b,
                   (void*)&hq, (void*)&bars, (void*)&out };
  hipLaunchCooperativeKernel((void*)k3_gru, dim3(256), dim3(256), args, 0, stream);
}

// Round 3
// 1130.725 us; speedup vs baseline: 1.7292x; 1.2100x over previous
//
#include <hip/hip_runtime.h>
#include <hip/hip_bf16.h>
#include <math.h>

// Problem: S=512, B=128, V=50257, D=300, H=512
#define S_LEN 512
#define B_N   128
#define D_EMB 300
#define KP    320   // D padded to multiple of 32 (zero-filled)
#define H_N   512

typedef __attribute__((ext_vector_type(8)))  short short8;       // 8 bf16 (4 VGPRs)
typedef __attribute__((ext_vector_type(8)))  unsigned short ushort8;
typedef __attribute__((ext_vector_type(4)))  unsigned int uint4v;
typedef __attribute__((ext_vector_type(4)))  float float4v;
typedef __attribute__((ext_vector_type(16))) float float16v;

__device__ __forceinline__ unsigned short f32_to_bf16(float f) {
  unsigned u = __float_as_uint(f);
  u = (u + 0x7fffu + ((u >> 16) & 1u)) >> 16;   // RNE
  return (unsigned short)u;
}
__device__ __forceinline__ float bf16_to_f32(unsigned short h) {
  return __uint_as_float(((unsigned)h) << 16);
}
__device__ __forceinline__ short8 as_short8(uint4v v) {
  union { uint4v u; short8 s; } c; c.u = v; return c.s;
}

// ---------------------------------------------------------------------------
// K1: embeds = embed_mat[ends]; xn = embeds / max(||embeds||,eps)
// writes xn as split bf16 (hi+lo), layout [b][s][KP], k 300..319 zero.
// ---------------------------------------------------------------------------
__global__ __launch_bounds__(256) void k1_embed_norm(
    const int* __restrict__ ends, const float* __restrict__ emb,
    unsigned short* __restrict__ xh, unsigned short* __restrict__ xl) {
  int wave = threadIdx.x >> 6, lane = threadIdx.x & 63;
  int vec = blockIdx.x * 4 + wave;            // vec = s*B + b (ends is [S][B])
  int b = vec & (B_N - 1), s = vec >> 7;
  int v = ends[vec];
  const float* row = emb + (size_t)v * D_EMB;
  float e0 = row[lane], e1 = row[lane + 64], e2 = row[lane + 128], e3 = row[lane + 192];
  float e4 = (lane + 256 < D_EMB) ? row[lane + 256] : 0.f;
  float ss = e0*e0 + e1*e1 + e2*e2 + e3*e3 + e4*e4;
  #pragma unroll
  for (int m = 1; m < 64; m <<= 1) ss += __shfl_xor(ss, m);
  float sc = 1.0f / fmaxf(sqrtf(ss), 1e-8f);
  size_t base = ((size_t)b * S_LEN + s) * KP;
  float xs[5] = { e0*sc, e1*sc, e2*sc, e3*sc, (lane + 256 < D_EMB) ? e4*sc : 0.f };
  #pragma unroll
  for (int i = 0; i < 5; ++i) {
    unsigned short hi = f32_to_bf16(xs[i]);
    unsigned short lo = f32_to_bf16(xs[i] - bf16_to_f32(hi));
    xh[base + lane + 64*i] = hi;
    xl[base + lane + 64*i] = lo;
  }
}

// ---------------------------------------------------------------------------
// K2: feats[i][b] = max_{j<i} dot(xn[i,b], xn[j,b]); feats[0]=0
// Split-bf16 MFMA 32x32x16 (hi*hi + hi*lo + lo*hi).
// R11: A-operand fragments loaded straight from global into registers
// (identical element mapping as the old LDS path; L2-hot after jc=0),
// LDS stages only B (22.5KB -> ~2x co-residency), grid is (b, ic) so all
// ic-chunks of a batch share one XCD L2 (same %8 mapping k3 relies on).
// ---------------------------------------------------------------------------
#define KC  80
#define LDP 88      // LDS row stride in ushorts (conflict-friendly, 16B aligned)

__global__ __launch_bounds__(256) void k2_feats(
    const unsigned short* __restrict__ xh, const unsigned short* __restrict__ xl,
    float* __restrict__ feats) {
  __shared__ __align__(16) unsigned short sBh[64*LDP], sBl[64*LDP];
  __shared__ float rbuf[4][32];
  int b   = blockIdx.x;          // 0..127 (b&7 selects XCD)
  int ic  = blockIdx.y;          // 0..7
  int tid = threadIdx.x;
  int wave = tid >> 6, lane = tid & 63;
  int itl = wave & 1, jtl = wave >> 1;
  int itg = ic * 2 + itl;        // global 32-row i-tile index
  size_t xbase = (size_t)b * S_LEN * KP;
  int arow0 = ic * 64;
  // my A row (m = lane&31) and k-quad offset
  const size_t arowoff = xbase + (size_t)(arow0 + itl * 32 + (lane & 31)) * KP
                       + (size_t)((lane >> 5) * 8);

  float rm[16];
  #pragma unroll
  for (int r = 0; r < 16; ++r) rm[r] = -INFINITY;

  for (int jc = 0; jc <= ic; ++jc) {
    int jt = jc * 2 + jtl;
    bool active = (jt <= itg);
    float16v acc;
    #pragma unroll
    for (int r = 0; r < 16; ++r) acc[r] = 0.f;

    for (int kc = 0; kc < 4; ++kc) {
      // A fragments: direct global->register (10 x 16B per lane)
      short8 a_h[5], a_l[5];
      #pragma unroll
      for (int ks = 0; ks < 5; ++ks) {
        size_t ga = arowoff + kc * KC + ks * 16;
        a_h[ks] = *(const short8*)&xh[ga];
        a_l[ks] = *(const short8*)&xl[ga];
      }
      __syncthreads();
      for (int u = tid; u < 640; u += 256) {     // 64 rows x 10 16B-segs (B only)
        int r = u / 10, sg = u % 10;
        size_t gb = xbase + (size_t)(jc*64 + r) * KP + kc*KC + sg*8;
        int la = r * LDP + sg * 8;
        *(ushort8*)&sBh[la] = *(const ushort8*)&xh[gb];
        *(ushort8*)&sBl[la] = *(const ushort8*)&xl[gb];
      }
      __syncthreads();
      if (active) {
        int br = (jtl*32 + (lane & 31)) * LDP;
        int kq = (lane >> 5) * 8;
        #pragma unroll
        for (int ks = 0; ks < 5; ++ks) {
          short8 b_h = *(const short8*)&sBh[br + ks*16 + kq];
          short8 b_l = *(const short8*)&sBl[br + ks*16 + kq];
          acc = __builtin_amdgcn_mfma_f32_32x32x16_bf16(a_h[ks], b_h, acc, 0, 0, 0);
          acc = __builtin_amdgcn_mfma_f32_32x32x16_bf16(a_h[ks], b_l, acc, 0, 0, 0);
          acc = __builtin_amdgcn_mfma_f32_32x32x16_bf16(a_l[ks], b_h, acc, 0, 0, 0);
        }
      }
    }
    if (active) {
      int colg = jt * 32 + (lane & 31);
      #pragma unroll
      for (int r = 0; r < 16; ++r) {
        int rowg = itg * 32 + (r & 3) + 8*(r >> 2) + 4*(lane >> 5);
        float v = acc[r];
        if (jt == itg && colg >= rowg) v = -INFINITY;  // causal: j<i
        rm[r] = fmaxf(rm[r], v);
      }
    }
  }
  #pragma unroll
  for (int r = 0; r < 16; ++r) {
    float v = rm[r];
    v = fmaxf(v, __shfl_xor(v, 1));
    v = fmaxf(v, __shfl_xor(v, 2));
    v = fmaxf(v, __shfl_xor(v, 4));
    v = fmaxf(v, __shfl_xor(v, 8));
    v = fmaxf(v, __shfl_xor(v, 16));
    rm[r] = v;
  }
  if ((lane & 31) == 0) {
    int half = lane >> 5;
    #pragma unroll
    for (int r = 0; r < 16; ++r)
      rbuf[wave][(r & 3) + 8*(r >> 2) + 4*half] = rm[r];
  }
  __syncthreads();
  if (tid < 64) {   // merge jt-parities, write feats
    int it2 = tid >> 5, rl = tid & 31;
    float v = fmaxf(rbuf[it2][rl], rbuf[it2 + 2][rl]);
    int i = ic * 64 + it2 * 32 + rl;
    feats[i * B_N + b] = (i == 0) ? 0.0f : v;
  }
}

// ---------------------------------------------------------------------------
// K3: GRU, persistent cooperative kernel. 256 WGs x 256 thr.
// FROZEN at the R8 skeleton (sync protocol unchanged since):
//   wg-scope producer stores -> dirty in shared XCD L2; per-WG flag
//   bars[g*32+s]; all-wave 32-flag poll with s_sleep; post-store vmcnt(0)
//   + __syncthreads + tid0 flag store.
// LEDGER: per-wave flag fanouts fast-fail 3/3 (R5/R6/R9, mechanism unknown);
// counter-RMW flags regress (R10); poison-spin data-as-signal regresses
// +16% (R12); R13 coalesced consumer load (8x dwordx4 sc1) -360us — the
// consumer L2 fan-out burst IS the critical path.
// R14 (this round): FRAGMENT-MAJOR SPLIT hi/lo h LAYOUT.
//   hi-array ushort idx I = (g*16 + w*4 + ks)*512 + lane*8 + e  (lo at
//   +65536 per parity). Consumer: 8x global_load_dwordx4, each covering a
//   fully-contiguous 1KB block (100% segment efficiency vs R13's 50%), and
//   the loaded regs ARE the MFMA fragments (R13's ~32 v_mov unpack gone).
//   Producer: 2-round shfl_xor pack -> same 128 x 8B wg-scope stores per WG
//   as before (drain/flag path identical).
// ---------------------------------------------------------------------------
#define HW64 (B_N * H_N / 2)   // 8B words per parity buffer (= 32768)

__global__ __launch_bounds__(256, 1) void k3_gru(
    const float* __restrict__ feats,
    const float* __restrict__ w_ih, const float* __restrict__ w_hh,
    const float* __restrict__ b_ih, const float* __restrict__ b_hh,
    const float* __restrict__ fc_w, const float* __restrict__ fc_b,
    unsigned long long* __restrict__ hq, unsigned int* __restrict__ bars,
    float* __restrict__ out) {
  __shared__ float red[4][3][16][17];
  __shared__ float osum[256];
  int tid = threadIdx.x;
  int wave = tid >> 6, lane = tid & 63;
  int g = blockIdx.x & 7, s = blockIdx.x >> 3;

  // --- stationary W_hh fragments in registers (B-operand: n=lane&15, k=quad*8+j)
  short8 wfh[3][4], wfl[3][4];
  {
    int nloc = lane & 15;
    int kq = (lane >> 4) * 8;
    #pragma unroll
    for (int gt = 0; gt < 3; ++gt) {
      const float* wr = w_hh + (size_t)(gt * H_N + s * 16 + nloc) * H_N;
      #pragma unroll
      for (int ks = 0; ks < 4; ++ks) {
        int k0 = wave * 128 + ks * 32 + kq;
        short8 h8, l8;
        #pragma unroll
        for (int j = 0; j < 8; ++j) {
          float wv = wr[k0 + j];
          unsigned short hi = f32_to_bf16(wv);
          unsigned short lo = f32_to_bf16(wv - bf16_to_f32(hi));
          h8[j] = (short)hi; l8[j] = (short)lo;
        }
        wfh[gt][ks] = h8; wfl[gt][ks] = l8;
      }
    }
  }
  // --- per-thread gate constants: thread = (bb, jj)
  int bb = tid >> 4, jj = tid & 15;
  int jr = s * 16 + jj;
  float wihr = w_ih[jr], wihz = w_ih[H_N + jr], wihn = w_ih[2*H_N + jr];
  float bir = b_ih[jr],  biz = b_ih[H_N + jr],  bin_ = b_ih[2*H_N + jr];
  float bhr = b_hh[jr],  bhz = b_hh[H_N + jr],  bhn = b_hh[2*H_N + jr];
  float fcw = fc_w[jr];
  int gb = g * 16 + bb;
  float h_old = 0.f;
  const unsigned int* fp = bars + g * 32 + (lane & 31);  // this group's 32 flags
  unsigned int* myflag = bars + g * 32 + s;

  // R14 producer indexing: j = s*16+jj -> w=s>>3, ks=(s>>1)&3, q=(2s+(jj>>3))&3
  const int qp  = (2 * s + (jj >> 3)) & 3;
  const int C0p = (g * 16 + (s >> 3) * 4 + ((s >> 1) & 3)) * 512;  // ushort idx
  const size_t uhi = (size_t)((C0p + qp * 128 + bb * 8 + (jj & 4)) >> 2); // u64 idx
  const int sel = jj & 3;
  // R14 consumer base (ushort offset within parity's hi array)
  const size_t cbase = (size_t)(g * 16 + wave * 4) * 512 + (size_t)lane * 8;

  for (int t = 0; t < S_LEN; ++t) {
    // feats load hoisted above the poll — independent, overlaps the spin
    float x = feats[t * B_N + gb];
    float sr = 0.f, sz = 0.f, sn = 0.f;
    if (t > 0) {
      // ---- wait: all 32 WGs stored h_{t-1} (flag >= t). every wave polls.
      {
        const unsigned tgt = (unsigned)t;
        for (;;) {
          unsigned f = __hip_atomic_load(fp, __ATOMIC_RELAXED, __HIP_MEMORY_SCOPE_AGENT);
          if (__ballot(f < tgt) == 0ull) break;
          __builtin_amdgcn_s_sleep(1);
        }
        asm volatile("" ::: "memory");
      }
      const unsigned short* hh =
          (const unsigned short*)(hq + (size_t)((t - 1) & 1) * HW64);
      const unsigned short* hbase = hh + cbase;        // hi fragments
      const unsigned short* lbase = hbase + 65536;     // lo fragments
      // 8x dwordx4 sc1 (L1-bypass), each 64-lane instr = 1KB contiguous.
      uint4v rh0, rh1, rh2, rh3, rl0, rl1, rl2, rl3;
      asm volatile(
        "global_load_dwordx4 %0, %8, off sc1\n\t"
        "global_load_dwordx4 %1, %8, off offset:1024 sc1\n\t"
        "global_load_dwordx4 %2, %8, off offset:2048 sc1\n\t"
        "global_load_dwordx4 %3, %8, off offset:3072 sc1\n\t"
        "global_load_dwordx4 %4, %9, off sc1\n\t"
        "global_load_dwordx4 %5, %9, off offset:1024 sc1\n\t"
        "global_load_dwordx4 %6, %9, off offset:2048 sc1\n\t"
        "global_load_dwordx4 %7, %9, off offset:3072 sc1\n\t"
        "s_waitcnt vmcnt(0)"
        : "=&v"(rh0), "=&v"(rh1), "=&v"(rh2), "=&v"(rh3),
          "=&v"(rl0), "=&v"(rl1), "=&v"(rl2), "=&v"(rl3)
        : "v"(hbase), "v"(lbase)
        : "memory");
      short8 ah[4] = { as_short8(rh0), as_short8(rh1), as_short8(rh2), as_short8(rh3) };
      short8 al[4] = { as_short8(rl0), as_short8(rl1), as_short8(rl2), as_short8(rl3) };
      float4v a0, a1, a2;
      #pragma unroll
      for (int r = 0; r < 4; ++r) { a0[r] = 0.f; a1[r] = 0.f; a2[r] = 0.f; }
      #pragma unroll
      for (int ks = 0; ks < 4; ++ks) {
        a0 = __builtin_amdgcn_mfma_f32_16x16x32_bf16(ah[ks], wfh[0][ks], a0, 0,0,0);
        a1 = __builtin_amdgcn_mfma_f32_16x16x32_bf16(ah[ks], wfh[1][ks], a1, 0,0,0);
        a2 = __builtin_amdgcn_mfma_f32_16x16x32_bf16(ah[ks], wfh[2][ks], a2, 0,0,0);
        a0 = __builtin_amdgcn_mfma_f32_16x16x32_bf16(ah[ks], wfl[0][ks], a0, 0,0,0);
        a1 = __builtin_amdgcn_mfma_f32_16x16x32_bf16(ah[ks], wfl[1][ks], a1, 0,0,0);
        a2 = __builtin_amdgcn_mfma_f32_16x16x32_bf16(ah[ks], wfl[2][ks], a2, 0,0,0);
        a0 = __builtin_amdgcn_mfma_f32_16x16x32_bf16(al[ks], wfh[0][ks], a0, 0,0,0);
        a1 = __builtin_amdgcn_mfma_f32_16x16x32_bf16(al[ks], wfh[1][ks], a1, 0,0,0);
        a2 = __builtin_amdgcn_mfma_f32_16x16x32_bf16(al[ks], wfh[2][ks], a2, 0,0,0);
      }
      // C/D: row(batch)=(lane>>4)*4+reg, col(j)=lane&15. Scalar writes, padded.
      int colw = lane & 15, roww = (lane >> 4) * 4;
      #pragma unroll
      for (int r = 0; r < 4; ++r) {
        red[wave][0][roww + r][colw] = a0[r];
        red[wave][1][roww + r][colw] = a1[r];
        red[wave][2][roww + r][colw] = a2[r];
      }
      __syncthreads();
      sr = red[0][0][bb][jj] + red[1][0][bb][jj] + red[2][0][bb][jj] + red[3][0][bb][jj];
      sz = red[0][1][bb][jj] + red[1][1][bb][jj] + red[2][1][bb][jj] + red[3][1][bb][jj];
      sn = red[0][2][bb][jj] + red[1][2][bb][jj] + red[2][2][bb][jj] + red[3][2][bb][jj];
    }
    // gates: exact identities on fast exp; clamp to dodge inf/inf
    float ar_ = fminf(fmaxf(x * wihr + bir + sr + bhr, -30.f), 30.f);
    float az_ = fminf(fmaxf(x * wihz + biz + sz + bhz, -30.f), 30.f);
    float r_ = __builtin_amdgcn_rcpf(1.f + __expf(-ar_));
    float z_ = __builtin_amdgcn_rcpf(1.f + __expf(-az_));
    float an_ = fminf(fmaxf(x * wihn + bin_ + r_ * (sn + bhn), -30.f), 30.f);
    float en = __expf(-2.f * an_);
    float n_ = (1.f - en) * __builtin_amdgcn_rcpf(1.f + en);
    float h_new = (1.f - z_) * n_ + z_ * h_old;
    h_old = h_new;
    if (t < S_LEN - 1) {
      unsigned short hi16 = f32_to_bf16(h_new);
      unsigned short lo16 = f32_to_bf16(h_new - bf16_to_f32(hi16));
      // R14: 2-round pack of 8-element runs (lanes e=jj&7 within 8-group).
      unsigned myh = hi16, myl = lo16;
      unsigned oh = (unsigned)__shfl_xor((int)myh, 1);
      unsigned ol = (unsigned)__shfl_xor((int)myl, 1);
      bool od1 = (jj & 1) != 0;
      unsigned pH = od1 ? (oh | (myh << 16)) : (myh | (oh << 16));  // [e even | e odd]
      unsigned pL = od1 ? (ol | (myl << 16)) : (myl | (ol << 16));
      unsigned qh = (unsigned)__shfl_xor((int)pH, 2);
      unsigned ql = (unsigned)__shfl_xor((int)pL, 2);
      bool od2 = (jj & 2) != 0;
      unsigned lowH = od2 ? qh : pH, highH = od2 ? pH : qh;   // quad e0..e3
      unsigned lowL = od2 ? ql : pL, highL = od2 ? pL : ql;
      unsigned long long* pbase = hq + (size_t)(t & 1) * HW64;
      if (sel == 0) {
        unsigned long long wv = (unsigned long long)lowH
                              | ((unsigned long long)highH << 32);
        __hip_atomic_store(pbase + uhi, wv,
                           __ATOMIC_RELAXED, __HIP_MEMORY_SCOPE_WORKGROUP);
      } else if (sel == 1) {
        unsigned long long wv = (unsigned long long)lowL
                              | ((unsigned long long)highL << 32);
        __hip_atomic_store(pbase + 16384 + uhi, wv,
                           __ATOMIC_RELAXED, __HIP_MEMORY_SCOPE_WORKGROUP);
      }
      // drain own stores (ack at L2), WG barrier, then flag (wg-scope)
      asm volatile("s_waitcnt vmcnt(0)" ::: "memory");
      __syncthreads();
      if (tid == 0)
        __hip_atomic_store(myflag, (unsigned)(t + 1),
                           __ATOMIC_RELAXED, __HIP_MEMORY_SCOPE_WORKGROUP);
    }
  }
  // --- epilogue: out[b] = h_last . fc_w + fc_b
  osum[tid] = h_old * fcw;
  __syncthreads();
  if (jj == 0) {
    float acc = 0.f;
    #pragma unroll
    for (int q = 0; q < 16; ++q) acc += osum[bb * 16 + q];
    if (s == 0) acc += fc_b[0];
    atomicAdd(&out[gb], acc);
  }
}

// ---------------------------------------------------------------------------
extern "C" void kernel_launch(void* const* d_in, const int* in_sizes, int n_in,
                              void* d_out, int out_size, void* d_ws, size_t ws_size,
                              hipStream_t stream) {
  (void)in_sizes; (void)n_in; (void)out_size; (void)ws_size;
  const int*   ends = (const int*)d_in[1];
  const float* emb  = (const float*)d_in[3];
  const float* w_ih = (const float*)d_in[4];
  const float* w_hh = (const float*)d_in[5];
  const float* b_ih = (const float*)d_in[6];
  const float* b_hh = (const float*)d_in[7];
  const float* fc_w = (const float*)d_in[8];
  const float* fc_b = (const float*)d_in[9];
  float* out = (float*)d_out;

  size_t xn_elems = (size_t)B_N * S_LEN * KP;
  unsigned short* xh = (unsigned short*)d_ws;
  unsigned short* xl = xh + xn_elems;
  float* feats = (float*)(xl + xn_elems);
  unsigned long long* hq = (unsigned long long*)(feats + S_LEN * B_N);
  unsigned int* bars = (unsigned int*)(hq + 2 * (size_t)HW64);

  hipMemsetAsync(out, 0, sizeof(float) * B_N, stream);
  hipMemsetAsync(bars, 0, 4096, stream);   // 8 groups x 32 WG flags

  k1_embed_norm<<<dim3(S_LEN * B_N / 4), dim3(256), 0, stream>>>(ends, emb, xh, xl);
  k2_feats<<<dim3(B_N, 8), dim3(256), 0, stream>>>(xh, xl, feats);

  void* args[] = { (void*)&feats, (void*)&w_ih, (void*)&w_hh, (void*)&b_ih,
                   (void*)&b_hh, (void*)&fc_w, (void*)&fc_b,
                   (void*)&hq, (void*)&bars, (void*)&out };
  hipLaunchCooperativeKernel((void*)k3_gru, dim3(256), dim3(256), args, 0, stream);
}

// Round 4
// 1107.753 us; speedup vs baseline: 1.7650x; 1.0207x over previous
//
#include <hip/hip_runtime.h>
#include <hip/hip_bf16.h>
#include <math.h>

// Problem: S=512, B=128, V=50257, D=300, H=512
#define S_LEN 512
#define B_N   128
#define D_EMB 300
#define KP    320   // D padded to multiple of 32 (zero-filled)
#define H_N   512

typedef __attribute__((ext_vector_type(8)))  short short8;       // 8 bf16 (4 VGPRs)
typedef __attribute__((ext_vector_type(8)))  unsigned short ushort8;
typedef __attribute__((ext_vector_type(4)))  unsigned int uint4v;
typedef __attribute__((ext_vector_type(4)))  float float4v;
typedef __attribute__((ext_vector_type(16))) float float16v;

__device__ __forceinline__ unsigned short f32_to_bf16(float f) {
  unsigned u = __float_as_uint(f);
  u = (u + 0x7fffu + ((u >> 16) & 1u)) >> 16;   // RNE
  return (unsigned short)u;
}
__device__ __forceinline__ float bf16_to_f32(unsigned short h) {
  return __uint_as_float(((unsigned)h) << 16);
}
__device__ __forceinline__ short8 as_short8(uint4v v) {
  union { uint4v u; short8 s; } c; c.u = v; return c.s;
}

// ---------------------------------------------------------------------------
// K1: embeds = embed_mat[ends]; xn = embeds / max(||embeds||,eps)
// writes xn as split bf16 (hi+lo), layout [b][s][KP], k 300..319 zero.
// ---------------------------------------------------------------------------
__global__ __launch_bounds__(256) void k1_embed_norm(
    const int* __restrict__ ends, const float* __restrict__ emb,
    unsigned short* __restrict__ xh, unsigned short* __restrict__ xl) {
  int wave = threadIdx.x >> 6, lane = threadIdx.x & 63;
  int vec = blockIdx.x * 4 + wave;            // vec = s*B + b (ends is [S][B])
  int b = vec & (B_N - 1), s = vec >> 7;
  int v = ends[vec];
  const float* row = emb + (size_t)v * D_EMB;
  float e0 = row[lane], e1 = row[lane + 64], e2 = row[lane + 128], e3 = row[lane + 192];
  float e4 = (lane + 256 < D_EMB) ? row[lane + 256] : 0.f;
  float ss = e0*e0 + e1*e1 + e2*e2 + e3*e3 + e4*e4;
  #pragma unroll
  for (int m = 1; m < 64; m <<= 1) ss += __shfl_xor(ss, m);
  float sc = 1.0f / fmaxf(sqrtf(ss), 1e-8f);
  size_t base = ((size_t)b * S_LEN + s) * KP;
  float xs[5] = { e0*sc, e1*sc, e2*sc, e3*sc, (lane + 256 < D_EMB) ? e4*sc : 0.f };
  #pragma unroll
  for (int i = 0; i < 5; ++i) {
    unsigned short hi = f32_to_bf16(xs[i]);
    unsigned short lo = f32_to_bf16(xs[i] - bf16_to_f32(hi));
    xh[base + lane + 64*i] = hi;
    xl[base + lane + 64*i] = lo;
  }
}

// ---------------------------------------------------------------------------
// K2: feats[i][b] = max_{j<i} dot(xn[i,b], xn[j,b]); feats[0]=0
// Split-bf16 MFMA 32x32x16 (hi*hi + hi*lo + lo*hi).
// R11: A-operand fragments loaded straight from global into registers
// (identical element mapping as the old LDS path; L2-hot after jc=0),
// LDS stages only B (22.5KB -> ~2x co-residency), grid is (b, ic) so all
// ic-chunks of a batch share one XCD L2 (same %8 mapping k3 relies on).
// ---------------------------------------------------------------------------
#define KC  80
#define LDP 88      // LDS row stride in ushorts (conflict-friendly, 16B aligned)

__global__ __launch_bounds__(256) void k2_feats(
    const unsigned short* __restrict__ xh, const unsigned short* __restrict__ xl,
    float* __restrict__ feats) {
  __shared__ __align__(16) unsigned short sBh[64*LDP], sBl[64*LDP];
  __shared__ float rbuf[4][32];
  int b   = blockIdx.x;          // 0..127 (b&7 selects XCD)
  int ic  = blockIdx.y;          // 0..7
  int tid = threadIdx.x;
  int wave = tid >> 6, lane = tid & 63;
  int itl = wave & 1, jtl = wave >> 1;
  int itg = ic * 2 + itl;        // global 32-row i-tile index
  size_t xbase = (size_t)b * S_LEN * KP;
  int arow0 = ic * 64;
  // my A row (m = lane&31) and k-quad offset
  const size_t arowoff = xbase + (size_t)(arow0 + itl * 32 + (lane & 31)) * KP
                       + (size_t)((lane >> 5) * 8);

  float rm[16];
  #pragma unroll
  for (int r = 0; r < 16; ++r) rm[r] = -INFINITY;

  for (int jc = 0; jc <= ic; ++jc) {
    int jt = jc * 2 + jtl;
    bool active = (jt <= itg);
    float16v acc;
    #pragma unroll
    for (int r = 0; r < 16; ++r) acc[r] = 0.f;

    for (int kc = 0; kc < 4; ++kc) {
      // A fragments: direct global->register (10 x 16B per lane)
      short8 a_h[5], a_l[5];
      #pragma unroll
      for (int ks = 0; ks < 5; ++ks) {
        size_t ga = arowoff + kc * KC + ks * 16;
        a_h[ks] = *(const short8*)&xh[ga];
        a_l[ks] = *(const short8*)&xl[ga];
      }
      __syncthreads();
      for (int u = tid; u < 640; u += 256) {     // 64 rows x 10 16B-segs (B only)
        int r = u / 10, sg = u % 10;
        size_t gb = xbase + (size_t)(jc*64 + r) * KP + kc*KC + sg*8;
        int la = r * LDP + sg * 8;
        *(ushort8*)&sBh[la] = *(const ushort8*)&xh[gb];
        *(ushort8*)&sBl[la] = *(const ushort8*)&xl[gb];
      }
      __syncthreads();
      if (active) {
        int br = (jtl*32 + (lane & 31)) * LDP;
        int kq = (lane >> 5) * 8;
        #pragma unroll
        for (int ks = 0; ks < 5; ++ks) {
          short8 b_h = *(const short8*)&sBh[br + ks*16 + kq];
          short8 b_l = *(const short8*)&sBl[br + ks*16 + kq];
          acc = __builtin_amdgcn_mfma_f32_32x32x16_bf16(a_h[ks], b_h, acc, 0, 0, 0);
          acc = __builtin_amdgcn_mfma_f32_32x32x16_bf16(a_h[ks], b_l, acc, 0, 0, 0);
          acc = __builtin_amdgcn_mfma_f32_32x32x16_bf16(a_l[ks], b_h, acc, 0, 0, 0);
        }
      }
    }
    if (active) {
      int colg = jt * 32 + (lane & 31);
      #pragma unroll
      for (int r = 0; r < 16; ++r) {
        int rowg = itg * 32 + (r & 3) + 8*(r >> 2) + 4*(lane >> 5);
        float v = acc[r];
        if (jt == itg && colg >= rowg) v = -INFINITY;  // causal: j<i
        rm[r] = fmaxf(rm[r], v);
      }
    }
  }
  #pragma unroll
  for (int r = 0; r < 16; ++r) {
    float v = rm[r];
    v = fmaxf(v, __shfl_xor(v, 1));
    v = fmaxf(v, __shfl_xor(v, 2));
    v = fmaxf(v, __shfl_xor(v, 4));
    v = fmaxf(v, __shfl_xor(v, 8));
    v = fmaxf(v, __shfl_xor(v, 16));
    rm[r] = v;
  }
  if ((lane & 31) == 0) {
    int half = lane >> 5;
    #pragma unroll
    for (int r = 0; r < 16; ++r)
      rbuf[wave][(r & 3) + 8*(r >> 2) + 4*half] = rm[r];
  }
  __syncthreads();
  if (tid < 64) {   // merge jt-parities, write feats
    int it2 = tid >> 5, rl = tid & 31;
    float v = fmaxf(rbuf[it2][rl], rbuf[it2 + 2][rl]);
    int i = ic * 64 + it2 * 32 + rl;
    feats[i * B_N + b] = (i == 0) ? 0.0f : v;
  }
}

// ---------------------------------------------------------------------------
// K3: GRU, persistent cooperative kernel. 256 WGs x 256 thr.
// FROZEN R8 signal skeleton: wg-scope producer stores -> vmcnt(0) ->
// __syncthreads -> tid0 WG-flag store; consumer flag poll with s_sleep.
// LEDGER: per-wave PRODUCER flag fanouts fast-fail 3/3 (R5/R6/R9);
// counter-RMW flags regress (R10); poison-spin data-as-signal +16% (R12);
// R13 coalesced consumer load -360us; R14 fragment-major layout -253us
// (consumer L2 segment traffic was the dominant term, now 100% efficient).
// R15 (this round), three independent changes, skeleton untouched:
//  a) per-wave 8-flag poll: wave w's fragments come only from producers
//     s in [8w,8w+8) -> poll those 8 flags, absorbing inter-WG skew
//     (max over 8, not 32) and overlapping residual skew with MFMA.
//  b) 16B producer stores: one extra shfl_xor(4) allgather round builds
//     the full 8-elem run; 64x dwordx4 replaces 128x 8B stores -> halves
//     outstanding acks behind the critical vmcnt(0) drain.
//  c) float4 LDS reduce red2[4][16][16] (ds_write_b128/ds_read_b128,
//     bank-balanced 8 words/bank) replaces 12+12 scalar ops with 4-way
//     write conflicts. Same add order -> bit-identical.
// ---------------------------------------------------------------------------
#define HW64 (B_N * H_N / 2)   // 8B words per parity buffer (= 32768)

__global__ __launch_bounds__(256, 1) void k3_gru(
    const float* __restrict__ feats,
    const float* __restrict__ w_ih, const float* __restrict__ w_hh,
    const float* __restrict__ b_ih, const float* __restrict__ b_hh,
    const float* __restrict__ fc_w, const float* __restrict__ fc_b,
    unsigned long long* __restrict__ hq, unsigned int* __restrict__ bars,
    float* __restrict__ out) {
  __shared__ __align__(16) float4v red2[4][16][16];   // [wave][batch][j] = {r,z,n,pad}
  __shared__ float osum[256];
  int tid = threadIdx.x;
  int wave = tid >> 6, lane = tid & 63;
  int g = blockIdx.x & 7, s = blockIdx.x >> 3;

  // --- stationary W_hh fragments in registers (B-operand: n=lane&15, k=quad*8+j)
  short8 wfh[3][4], wfl[3][4];
  {
    int nloc = lane & 15;
    int kq = (lane >> 4) * 8;
    #pragma unroll
    for (int gt = 0; gt < 3; ++gt) {
      const float* wr = w_hh + (size_t)(gt * H_N + s * 16 + nloc) * H_N;
      #pragma unroll
      for (int ks = 0; ks < 4; ++ks) {
        int k0 = wave * 128 + ks * 32 + kq;
        short8 h8, l8;
        #pragma unroll
        for (int j = 0; j < 8; ++j) {
          float wv = wr[k0 + j];
          unsigned short hi = f32_to_bf16(wv);
          unsigned short lo = f32_to_bf16(wv - bf16_to_f32(hi));
          h8[j] = (short)hi; l8[j] = (short)lo;
        }
        wfh[gt][ks] = h8; wfl[gt][ks] = l8;
      }
    }
  }
  // --- per-thread gate constants: thread = (bb, jj)
  int bb = tid >> 4, jj = tid & 15;
  int jr = s * 16 + jj;
  float wihr = w_ih[jr], wihz = w_ih[H_N + jr], wihn = w_ih[2*H_N + jr];
  float bir = b_ih[jr],  biz = b_ih[H_N + jr],  bin_ = b_ih[2*H_N + jr];
  float bhr = b_hh[jr],  bhz = b_hh[H_N + jr],  bhn = b_hh[2*H_N + jr];
  float fcw = fc_w[jr];
  int gb = g * 16 + bb;
  float h_old = 0.f;
  // R15a: wave w polls only its 8 producers s in [8w, 8w+8)
  const unsigned int* fp = bars + g * 32 + wave * 8 + (lane & 7);
  unsigned int* myflag = bars + g * 32 + s;

  // R14/R15 producer indexing: j = s*16+jj
  //   fragment C = g*16 + (s>>3)*4 + ((s>>1)&3); q = (2s + (jj>>3))&3
  const int Cp = g * 16 + (s >> 3) * 4 + ((s >> 1) & 3);
  const int qp = (2 * s + (jj >> 3)) & 3;
  const size_t prodoff = (size_t)Cp * 512 + (size_t)qp * 128 + (size_t)bb * 8;
  // consumer base (ushort offset within parity's hi array)
  const size_t cbase = (size_t)(g * 16 + wave * 4) * 512 + (size_t)lane * 8;

  for (int t = 0; t < S_LEN; ++t) {
    // feats load hoisted above the poll — independent, overlaps the spin
    float x = feats[t * B_N + gb];
    float sr = 0.f, sz = 0.f, sn = 0.f;
    if (t > 0) {
      // ---- wait: this wave's 8 producers stored h_{t-1} (flag >= t)
      {
        const unsigned tgt = (unsigned)t;
        for (;;) {
          unsigned f = __hip_atomic_load(fp, __ATOMIC_RELAXED, __HIP_MEMORY_SCOPE_AGENT);
          if (__ballot(f < tgt) == 0ull) break;
          __builtin_amdgcn_s_sleep(1);
        }
        asm volatile("" ::: "memory");
      }
      const unsigned short* hh =
          (const unsigned short*)(hq + (size_t)((t - 1) & 1) * HW64);
      const unsigned short* hbase = hh + cbase;        // hi fragments
      const unsigned short* lbase = hbase + 65536;     // lo fragments
      // 8x dwordx4 sc1 (L1-bypass), each 64-lane instr = 1KB contiguous.
      uint4v rh0, rh1, rh2, rh3, rl0, rl1, rl2, rl3;
      asm volatile(
        "global_load_dwordx4 %0, %8, off sc1\n\t"
        "global_load_dwordx4 %1, %8, off offset:1024 sc1\n\t"
        "global_load_dwordx4 %2, %8, off offset:2048 sc1\n\t"
        "global_load_dwordx4 %3, %8, off offset:3072 sc1\n\t"
        "global_load_dwordx4 %4, %9, off sc1\n\t"
        "global_load_dwordx4 %5, %9, off offset:1024 sc1\n\t"
        "global_load_dwordx4 %6, %9, off offset:2048 sc1\n\t"
        "global_load_dwordx4 %7, %9, off offset:3072 sc1\n\t"
        "s_waitcnt vmcnt(0)"
        : "=&v"(rh0), "=&v"(rh1), "=&v"(rh2), "=&v"(rh3),
          "=&v"(rl0), "=&v"(rl1), "=&v"(rl2), "=&v"(rl3)
        : "v"(hbase), "v"(lbase)
        : "memory");
      short8 ah[4] = { as_short8(rh0), as_short8(rh1), as_short8(rh2), as_short8(rh3) };
      short8 al[4] = { as_short8(rl0), as_short8(rl1), as_short8(rl2), as_short8(rl3) };
      float4v a0, a1, a2;
      #pragma unroll
      for (int r = 0; r < 4; ++r) { a0[r] = 0.f; a1[r] = 0.f; a2[r] = 0.f; }
      #pragma unroll
      for (int ks = 0; ks < 4; ++ks) {
        a0 = __builtin_amdgcn_mfma_f32_16x16x32_bf16(ah[ks], wfh[0][ks], a0, 0,0,0);
        a1 = __builtin_amdgcn_mfma_f32_16x16x32_bf16(ah[ks], wfh[1][ks], a1, 0,0,0);
        a2 = __builtin_amdgcn_mfma_f32_16x16x32_bf16(ah[ks], wfh[2][ks], a2, 0,0,0);
        a0 = __builtin_amdgcn_mfma_f32_16x16x32_bf16(ah[ks], wfl[0][ks], a0, 0,0,0);
        a1 = __builtin_amdgcn_mfma_f32_16x16x32_bf16(ah[ks], wfl[1][ks], a1, 0,0,0);
        a2 = __builtin_amdgcn_mfma_f32_16x16x32_bf16(ah[ks], wfl[2][ks], a2, 0,0,0);
        a0 = __builtin_amdgcn_mfma_f32_16x16x32_bf16(al[ks], wfh[0][ks], a0, 0,0,0);
        a1 = __builtin_amdgcn_mfma_f32_16x16x32_bf16(al[ks], wfh[1][ks], a1, 0,0,0);
        a2 = __builtin_amdgcn_mfma_f32_16x16x32_bf16(al[ks], wfh[2][ks], a2, 0,0,0);
      }
      // C/D: row(batch)=(lane>>4)*4+reg, col(j)=lane&15. float4 {r,z,n,pad}.
      int colw = lane & 15, roww = (lane >> 4) * 4;
      #pragma unroll
      for (int r = 0; r < 4; ++r) {
        float4v w; w[0] = a0[r]; w[1] = a1[r]; w[2] = a2[r]; w[3] = 0.f;
        red2[wave][roww + r][colw] = w;
      }
      __syncthreads();
      float4v s0 = red2[0][bb][jj], s1 = red2[1][bb][jj];
      float4v s2 = red2[2][bb][jj], s3 = red2[3][bb][jj];
      sr = s0[0] + s1[0] + s2[0] + s3[0];
      sz = s0[1] + s1[1] + s2[1] + s3[1];
      sn = s0[2] + s1[2] + s2[2] + s3[2];
    }
    // gates: exact identities on fast exp; clamp to dodge inf/inf
    float ar_ = fminf(fmaxf(x * wihr + bir + sr + bhr, -30.f), 30.f);
    float az_ = fminf(fmaxf(x * wihz + biz + sz + bhz, -30.f), 30.f);
    float r_ = __builtin_amdgcn_rcpf(1.f + __expf(-ar_));
    float z_ = __builtin_amdgcn_rcpf(1.f + __expf(-az_));
    float an_ = fminf(fmaxf(x * wihn + bin_ + r_ * (sn + bhn), -30.f), 30.f);
    float en = __expf(-2.f * an_);
    float n_ = (1.f - en) * __builtin_amdgcn_rcpf(1.f + en);
    float h_new = (1.f - z_) * n_ + z_ * h_old;
    h_old = h_new;
    if (t < S_LEN - 1) {
      unsigned short hi16 = f32_to_bf16(h_new);
      unsigned short lo16 = f32_to_bf16(h_new - bf16_to_f32(hi16));
      // R15b: 3-round shfl_xor allgather -> full 8-elem run in 4 dwords.
      unsigned myh = hi16, myl = lo16;
      unsigned oh = (unsigned)__shfl_xor((int)myh, 1);
      unsigned ol = (unsigned)__shfl_xor((int)myl, 1);
      bool od1 = (jj & 1) != 0;
      unsigned pH = od1 ? (oh | (myh << 16)) : (myh | (oh << 16));  // [e even|e odd]
      unsigned pL = od1 ? (ol | (myl << 16)) : (myl | (ol << 16));
      unsigned qh = (unsigned)__shfl_xor((int)pH, 2);
      unsigned ql = (unsigned)__shfl_xor((int)pL, 2);
      bool od2 = (jj & 2) != 0;
      unsigned h01 = od2 ? qh : pH, h23 = od2 ? pH : qh;   // pairs e01,e23 of 4-group
      unsigned l01 = od2 ? ql : pL, l23 = od2 ? pL : ql;
      unsigned xh01 = (unsigned)__shfl_xor((int)h01, 4);
      unsigned xh23 = (unsigned)__shfl_xor((int)h23, 4);
      unsigned xl01 = (unsigned)__shfl_xor((int)l01, 4);
      unsigned xl23 = (unsigned)__shfl_xor((int)l23, 4);
      bool od4 = (jj & 4) != 0;
      uint4v runH, runL;
      runH[0] = od4 ? xh01 : h01; runH[1] = od4 ? xh23 : h23;
      runH[2] = od4 ? h01 : xh01; runH[3] = od4 ? h23 : xh23;
      runL[0] = od4 ? xl01 : l01; runL[1] = od4 ? xl23 : l23;
      runL[2] = od4 ? l01 : xl01; runL[3] = od4 ? l23 : xl23;
      unsigned short* hh = (unsigned short*)(hq + (size_t)(t & 1) * HW64);
      if ((jj & 3) == 0) {   // jj=0,8: hi run; jj=4,12: lo run (q = (2s+(jj>>3))&3)
        if ((jj & 4) == 0) *(uint4v*)(hh + prodoff)         = runH;
        else               *(uint4v*)(hh + 65536 + prodoff) = runL;
      }
      // drain own stores (ack at L2), WG barrier, then flag (wg-scope)
      asm volatile("s_waitcnt vmcnt(0)" ::: "memory");
      __syncthreads();
      if (tid == 0)
        __hip_atomic_store(myflag, (unsigned)(t + 1),
                           __ATOMIC_RELAXED, __HIP_MEMORY_SCOPE_WORKGROUP);
    }
  }
  // --- epilogue: out[b] = h_last . fc_w + fc_b
  osum[tid] = h_old * fcw;
  __syncthreads();
  if (jj == 0) {
    float acc = 0.f;
    #pragma unroll
    for (int q = 0; q < 16; ++q) acc += osum[bb * 16 + q];
    if (s == 0) acc += fc_b[0];
    atomicAdd(&out[gb], acc);
  }
}

// ---------------------------------------------------------------------------
extern "C" void kernel_launch(void* const* d_in, const int* in_sizes, int n_in,
                              void* d_out, int out_size, void* d_ws, size_t ws_size,
                              hipStream_t stream) {
  (void)in_sizes; (void)n_in; (void)out_size; (void)ws_size;
  const int*   ends = (const int*)d_in[1];
  const float* emb  = (const float*)d_in[3];
  const float* w_ih = (const float*)d_in[4];
  const float* w_hh = (const float*)d_in[5];
  const float* b_ih = (const float*)d_in[6];
  const float* b_hh = (const float*)d_in[7];
  const float* fc_w = (const float*)d_in[8];
  const float* fc_b = (const float*)d_in[9];
  float* out = (float*)d_out;

  size_t xn_elems = (size_t)B_N * S_LEN * KP;
  unsigned short* xh = (unsigned short*)d_ws;
  unsigned short* xl = xh + xn_elems;
  float* feats = (float*)(xl + xn_elems);
  unsigned long long* hq = (unsigned long long*)(feats + S_LEN * B_N);
  unsigned int* bars = (unsigned int*)(hq + 2 * (size_t)HW64);

  hipMemsetAsync(out, 0, sizeof(float) * B_N, stream);
  hipMemsetAsync(bars, 0, 4096, stream);   // 8 groups x 32 WG flags

  k1_embed_norm<<<dim3(S_LEN * B_N / 4), dim3(256), 0, stream>>>(ends, emb, xh, xl);
  k2_feats<<<dim3(B_N, 8), dim3(256), 0, stream>>>(xh, xl, feats);

  void* args[] = { (void*)&feats, (void*)&w_ih, (void*)&w_hh, (void*)&b_ih,
                   (void*)&b_hh, (void*)&fc_w, (void*)&fc_b,
                   (void*)&hq, (void*)&bars, (void*)&out };
  hipLaunchCooperativeKernel((void*)k3_gru, dim3(256), dim3(256), args, 0, stream);
}